// Round 1
// baseline (174.941 us; speedup 1.0000x reference)
//
#include <hip/hip_runtime.h>
#include <stdint.h>

#define N_NODES 50000
#define DEG 32
#define FIN 512
#define FOUT 256

typedef __attribute__((ext_vector_type(4))) float f32x4;
typedef __attribute__((ext_vector_type(8))) short short8;

__device__ __forceinline__ unsigned short f2bf(float f) {
    union { float f; unsigned int u; } v; v.f = f;
    unsigned int u = v.u;
    return (unsigned short)((u + 0x7FFFu + ((u >> 16) & 1u)) >> 16);  // RNE
}
__device__ __forceinline__ float bf2f(unsigned short b) {
    union { unsigned int u; float f; } v; v.u = ((unsigned int)b) << 16;
    return v.f;
}

// ---------------- Kernel 1: W [512][256] fp32 -> Wt [256][512] bf16 ----------
__global__ void k_wt(const float* __restrict__ W, unsigned short* __restrict__ Wt) {
    int idx = blockIdx.x * 256 + threadIdx.x;   // 131072 total
    int c = idx >> 9;        // output row (FOUT)
    int k = idx & 511;       // output col (FIN)
    Wt[idx] = f2bf(W[k * FOUT + c]);
}

// ---------------- Kernel 2: seq = x @ W  (bf16 MFMA, fp32 accum) -------------
// Tile: BM=64 x BN=256(all), BK=32. 4 waves, wave w owns cols [w*64, w*64+64).
#define BM 64
#define BK 32
#define LDA 40   // padded row stride in ushorts (32 data + 8 pad = 80B)

__global__ __launch_bounds__(256, 2)
void k_gemm(const float* __restrict__ x, const unsigned short* __restrict__ Wt,
            unsigned short* __restrict__ seqb) {
    __shared__ unsigned short As[BM * LDA];     // 5120 B
    __shared__ unsigned short Bs[FOUT * LDA];   // 20480 B

    const int tid  = threadIdx.x;
    const int lane = tid & 63;
    const int w    = tid >> 6;          // wave 0..3
    const int row0 = blockIdx.x * BM;

    // A staging: thread t covers row=t>>2, 8 floats at col (t&3)*8
    const int ar = tid >> 2, aseg = tid & 3;
    int arow = row0 + ar; if (arow >= N_NODES) arow = N_NODES - 1;
    const float* aptr = x + (size_t)arow * FIN + aseg * 8;
    // B staging: thread t covers Wt row t (n-dim), 64B of k per step
    const unsigned short* bptr = Wt + (size_t)tid * FIN;

    f32x4 acc[4][4];
    f32x4 zero4 = {0.f, 0.f, 0.f, 0.f};
#pragma unroll
    for (int i = 0; i < 4; i++)
#pragma unroll
        for (int j = 0; j < 4; j++) acc[i][j] = zero4;

    const int fr = lane & 15;
    const int fq = lane >> 4;

    for (int kk = 0; kk < FIN; kk += BK) {
        // stage A: 8 fp32 -> 8 bf16
        float4 a0 = *(const float4*)(aptr + kk);
        float4 a1 = *(const float4*)(aptr + kk + 4);
        ushort4 p0 = { f2bf(a0.x), f2bf(a0.y), f2bf(a0.z), f2bf(a0.w) };
        ushort4 p1 = { f2bf(a1.x), f2bf(a1.y), f2bf(a1.z), f2bf(a1.w) };
        *(ushort4*)&As[ar * LDA + aseg * 8]     = p0;
        *(ushort4*)&As[ar * LDA + aseg * 8 + 4] = p1;
        // stage B: 4 x 16B bf16
#pragma unroll
        for (int j = 0; j < 4; j++) {
            uint4 bv = *(const uint4*)(const void*)(bptr + kk + j * 8);
            *(uint4*)(void*)&Bs[tid * LDA + j * 8] = bv;
        }
        __syncthreads();

        short8 af[4], bfr[4];
#pragma unroll
        for (int mi = 0; mi < 4; mi++)
            af[mi] = *(const short8*)(const void*)&As[(mi * 16 + fr) * LDA + fq * 8];
#pragma unroll
        for (int ni = 0; ni < 4; ni++)
            bfr[ni] = *(const short8*)(const void*)&Bs[(w * 64 + ni * 16 + fr) * LDA + fq * 8];
#pragma unroll
        for (int mi = 0; mi < 4; mi++)
#pragma unroll
            for (int ni = 0; ni < 4; ni++)
                acc[mi][ni] = __builtin_amdgcn_mfma_f32_16x16x32_bf16(
                    af[mi], bfr[ni], acc[mi][ni], 0, 0, 0);
        __syncthreads();
    }

    // epilogue: C/D layout col=lane&15, row=(lane>>4)*4+reg  [m89/m91]
#pragma unroll
    for (int mi = 0; mi < 4; mi++) {
#pragma unroll
        for (int r = 0; r < 4; r++) {
            int row = row0 + mi * 16 + fq * 4 + r;
            if (row < N_NODES) {
#pragma unroll
                for (int ni = 0; ni < 4; ni++) {
                    int col = w * 64 + ni * 16 + fr;
                    seqb[(size_t)row * FOUT + col] = f2bf(acc[mi][ni][r]);
                }
            }
        }
    }
}

// ---------------- Kernel 3: f1/f2 per node (wave per node) -------------------
__global__ __launch_bounds__(256, 4)
void k_f12(const unsigned short* __restrict__ seqb,
           const float* __restrict__ a1w, const float* __restrict__ a1b,
           const float* __restrict__ a2w, const float* __restrict__ a2b,
           float* __restrict__ f1, float* __restrict__ f2) {
    int node = (blockIdx.x * 256 + threadIdx.x) >> 6;
    int lane = threadIdx.x & 63;
    ushort4 s  = *(const ushort4*)(const void*)(seqb + (size_t)node * FOUT + lane * 4);
    float4 w1 = *(const float4*)(a1w + lane * 4);
    float4 w2 = *(const float4*)(a2w + lane * 4);
    float x0 = bf2f(s.x), x1 = bf2f(s.y), x2 = bf2f(s.z), x3 = bf2f(s.w);
    float d1 = x0 * w1.x + x1 * w1.y + x2 * w1.z + x3 * w1.w;
    float d2 = x0 * w2.x + x1 * w2.y + x2 * w2.z + x3 * w2.w;
#pragma unroll
    for (int off = 32; off; off >>= 1) {
        d1 += __shfl_xor(d1, off, 64);
        d2 += __shfl_xor(d2, off, 64);
    }
    if (lane == 0) {
        f1[node] = d1 + a1b[0];
        f2[node] = d2 + a2b[0];
    }
}

// ---------------- Kernel 4: edge logits + softmax + SpMM + elu ---------------
// One wave per node (rows sorted, exactly DEG=32 edges per node).
__global__ __launch_bounds__(256, 4)
void k_attn(const unsigned short* __restrict__ seqb,
            const float* __restrict__ f1, const float* __restrict__ f2,
            const float* __restrict__ bias_vals,
            const int* __restrict__ edge_col,
            const float* __restrict__ bias_out,
            float* __restrict__ out) {
    int node = (blockIdx.x * 256 + threadIdx.x) >> 6;
    int lane = threadIdx.x & 63;

    float e = -1e30f;
    int col = 0;
    if (lane < 32) {
        int eidx = node * DEG + lane;
        col = edge_col[eidx];
        float bv = bias_vals[eidx];
        e = bv * f1[node] + bv * f2[col];
        e = (e >= 0.f) ? e : 0.2f * e;         // leaky_relu 0.2
    }
    // softmax over the 32 edges (lower half-wave; width-32 groups independent)
    float m = e;
#pragma unroll
    for (int off = 16; off; off >>= 1) m = fmaxf(m, __shfl_xor(m, off, 32));
    float p = __expf(e - m);
    float s = p;
#pragma unroll
    for (int off = 16; off; off >>= 1) s += __shfl_xor(s, off, 32);
    float coef = p / s;                        // valid in lanes 0..31

    // SpMM: 64 lanes x 4 features (8B/lane gathers)
    float a0 = 0.f, a1 = 0.f, a2 = 0.f, a3 = 0.f;
    int fbase = lane * 4;
#pragma unroll
    for (int j = 0; j < DEG; j++) {
        float c  = __shfl(coef, j, 64);
        int   cj = __shfl(col,  j, 64);
        ushort4 sv = *(const ushort4*)(const void*)(seqb + (size_t)cj * FOUT + fbase);
        a0 += c * bf2f(sv.x);
        a1 += c * bf2f(sv.y);
        a2 += c * bf2f(sv.z);
        a3 += c * bf2f(sv.w);
    }
    float4 bo = *(const float4*)(bias_out + fbase);
    float4 r;
    r.x = a0 + bo.x; r.y = a1 + bo.y; r.z = a2 + bo.z; r.w = a3 + bo.w;
    r.x = (r.x > 0.f) ? r.x : expm1f(r.x);     // elu, alpha=1
    r.y = (r.y > 0.f) ? r.y : expm1f(r.y);
    r.z = (r.z > 0.f) ? r.z : expm1f(r.z);
    r.w = (r.w > 0.f) ? r.w : expm1f(r.w);
    *(float4*)(out + (size_t)node * FOUT + fbase) = r;
}

// ---------------------------------------------------------------------------
extern "C" void kernel_launch(void* const* d_in, const int* in_sizes, int n_in,
                              void* d_out, int out_size, void* d_ws, size_t ws_size,
                              hipStream_t stream) {
    const float* x         = (const float*)d_in[0];
    const float* W         = (const float*)d_in[1];
    const float* a1w       = (const float*)d_in[2];
    const float* a1b       = (const float*)d_in[3];
    const float* a2w       = (const float*)d_in[4];
    const float* a2b       = (const float*)d_in[5];
    const float* bias_out  = (const float*)d_in[6];
    const float* bias_vals = (const float*)d_in[7];
    // d_in[8] = edge_row: implicit (repeat(arange(N), 32)) — rows sorted, 32/node
    const int* edge_col    = (const int*)d_in[9];
    float* out = (float*)d_out;

    char* ws = (char*)d_ws;
    unsigned short* Wt   = (unsigned short*)ws;                         // 262144 B
    unsigned short* seqb = (unsigned short*)(ws + 262144);              // 25.6 MB
    float* f1 = (float*)(ws + 262144 + 25600000);                       // 200 KB
    float* f2 = (float*)(ws + 262144 + 25600000 + 200064);              // 200 KB

    hipLaunchKernelGGL(k_wt,   dim3(512),   dim3(256), 0, stream, W, Wt);
    hipLaunchKernelGGL(k_gemm, dim3((N_NODES + BM - 1) / BM), dim3(256), 0, stream,
                       x, Wt, seqb);
    hipLaunchKernelGGL(k_f12,  dim3(N_NODES / 4), dim3(256), 0, stream,
                       seqb, a1w, a1b, a2w, a2b, f1, f2);
    hipLaunchKernelGGL(k_attn, dim3(N_NODES / 4), dim3(256), 0, stream,
                       seqb, f1, f2, bias_vals, edge_col, bias_out, out);
}